// Round 1
// baseline (152.973 us; speedup 1.0000x reference)
//
#include <hip/hip_runtime.h>
#include <math.h>

#define G 256
#define M 256
#define NNODES (G*M)
#define EDGES (NNODES*16)   // 1,048,576
#define C 3
#define K 5
#define D 128
#define GM (G*M)            // 65536

// Workspace layout (floats):
//   u0  [C][G][M]  off 0        (196608)
//   mk0 [C][G][M]  off 196608   (196608)
//   u1  [C][G][M]  off 393216   (196608)
//   a0  [G][M]     off 589824   (65536)
//   ak0 [G][M]     off 655360   (65536)
//   a1  [G][M]     off 720896   (65536)
//   Mst [C][G]     off 786432   (768)
//   Ast [G]        off 787200   (256)
//   scalars        off 787456   [info_sum, l2_sum, path_sum]
#define OFF_U0   0
#define OFF_MK0  196608
#define OFF_U1   393216
#define OFF_A0   589824
#define OFF_AK0  655360
#define OFF_A1   720896
#define OFF_MST  786432
#define OFF_AST  787200
#define OFF_SCAL 787456
#define WS_FLOATS 787459

__device__ __forceinline__ float waveReduceSum(float v) {
    #pragma unroll
    for (int o = 32; o > 0; o >>= 1) v += __shfl_xor(v, o, 64);
    return v;
}
__device__ __forceinline__ float waveReduceMax(float v) {
    #pragma unroll
    for (int o = 32; o > 0; o >>= 1) v = fmaxf(v, __shfl_xor(v, o, 64));
    return v;
}

// Pass A: scatter row-s / col-t slices of Mdj & Adj, plus fused L_info/L_l2 sums.
__global__ void passA(const float* __restrict__ sij, const int* __restrict__ ei,
                      const int* __restrict__ s, const int* __restrict__ t,
                      float* __restrict__ ws) {
    int e = blockIdx.x * blockDim.x + threadIdx.x;
    float* u0  = ws + OFF_U0;
    float* mk0 = ws + OFF_MK0;
    float* a0  = ws + OFF_A0;
    float* ak0 = ws + OFF_AK0;
    float* Mst = ws + OFF_MST;
    float* Ast = ws + OFF_AST;
    float* scal = ws + OFF_SCAL;

    float info = 0.f, l2 = 0.f;
    if (e < EDGES) {
        int src = ei[e], dst = ei[EDGES + e];
        int g = src >> 8;             // batch[src] = src / M, M = 256
        int r = src & 255;
        int c = dst - (g << 8);       // dst local (same group by construction)
        int sg = s[g], tg = t[g];
        bool isr = (r == sg), isc = (c == tg);
        float v[C];
        #pragma unroll
        for (int cc = 0; cc < C; ++cc) v[cc] = sij[cc * EDGES + e];
        if (isr) {
            #pragma unroll
            for (int cc = 0; cc < C; ++cc) atomicAdd(&u0[cc * GM + (g << 8) + c], v[cc]);
            atomicAdd(&a0[(g << 8) + c], 1.0f);
        }
        if (isc) {
            #pragma unroll
            for (int cc = 0; cc < C; ++cc) atomicAdd(&mk0[cc * GM + (g << 8) + r], v[cc]);
            atomicAdd(&ak0[(g << 8) + r], 1.0f);
        }
        if (isr && isc) {
            #pragma unroll
            for (int cc = 0; cc < C; ++cc) atomicAdd(&Mst[cc * G + g], v[cc]);
            atomicAdd(&Ast[g], 1.0f);
        }
        #pragma unroll
        for (int cc = 0; cc < C; ++cc) {
            float x = v[cc];
            // infoloss with r=0.5: x*log(x/0.5+1e-6) + (1-x)*log((1-x)/(0.5+1e-6)+1e-6)
            info += x * logf(x * 2.0f + 1e-6f)
                  + (1.0f - x) * logf((1.0f - x) / 0.500001f + 1e-6f);
            l2 += x * x;
        }
    }
    // block reduction -> one atomic per block (precision + low contention)
    info = waveReduceSum(info);
    l2 = waveReduceSum(l2);
    __shared__ float sInfo[4], sL2[4];
    int wid = threadIdx.x >> 6, lane = threadIdx.x & 63;
    if (lane == 0) { sInfo[wid] = info; sL2[wid] = l2; }
    __syncthreads();
    if (threadIdx.x == 0) {
        float i2 = 0.f, l = 0.f;
        int nw = blockDim.x >> 6;
        for (int w = 0; w < nw; ++w) { i2 += sInfo[w]; l += sL2[w]; }
        atomicAdd(&scal[0], i2);
        atomicAdd(&scal[1], l);
    }
}

// Pass B: u1 = u0 @ Mdj (per class), a1 = a0 @ Adj (class-independent), edge-wise.
__global__ void passB(const float* __restrict__ sij, const int* __restrict__ ei,
                      float* __restrict__ ws) {
    int e = blockIdx.x * blockDim.x + threadIdx.x;
    if (e >= EDGES) return;
    const float* u0 = ws + OFF_U0;
    const float* a0 = ws + OFF_A0;
    float* u1 = ws + OFF_U1;
    float* a1 = ws + OFF_A1;
    int src = ei[e], dst = ei[EDGES + e];
    int g = src >> 8;
    int r = src & 255;
    int c = dst - (g << 8);
    float ar = a0[(g << 8) + r];
    if (ar == 0.0f) return;   // u0[g][r]==0 too (sij>0), nothing to scatter
    atomicAdd(&a1[(g << 8) + c], ar);
    #pragma unroll
    for (int cc = 0; cc < C; ++cc) {
        float ur = u0[cc * GM + (g << 8) + r];
        atomicAdd(&u1[cc * GM + (g << 8) + c], ur * sij[cc * EDGES + e]);
    }
}

// H_emb: per (c,g): scores = hg[g] . H[c][k], softmax over K, out = att @ H[c]
__global__ void embK(const float* __restrict__ hg, const float* __restrict__ H,
                     float* __restrict__ out) {
    int b = blockIdx.x;          // c*G + g
    int c = b / G, g = b - c * G;
    int d = threadIdx.x;         // 128 threads
    float h = hg[g * D + d];
    __shared__ float sc[K];
    __shared__ float att[K];
    if (threadIdx.x < K) sc[threadIdx.x] = 0.f;
    __syncthreads();
    #pragma unroll
    for (int k = 0; k < K; ++k) {
        float p = h * H[(c * K + k) * D + d];
        p = waveReduceSum(p);
        if ((threadIdx.x & 63) == 0) atomicAdd(&sc[k], p);
    }
    __syncthreads();
    if (threadIdx.x == 0) {
        float m = sc[0];
        #pragma unroll
        for (int k = 1; k < K; ++k) m = fmaxf(m, sc[k]);
        float sum = 0.f, ex[K];
        #pragma unroll
        for (int k = 0; k < K; ++k) { ex[k] = expf(sc[k] - m); sum += ex[k]; }
        #pragma unroll
        for (int k = 0; k < K; ++k) att[k] = ex[k] / sum;
    }
    __syncthreads();
    float o = 0.f;
    #pragma unroll
    for (int k = 0; k < K; ++k) o += att[k] * H[(c * K + k) * D + d];
    out[(c * G + g) * D + d] = o;
}

// Path loss finalize: per (c,g) block max over M, then log -> scalar accumulator.
__global__ void pathK(const float* __restrict__ pw, float* __restrict__ ws) {
    int b = blockIdx.x;          // c*G + g
    int c = b / G, g = b - c * G;
    int x = threadIdx.x;         // 256 threads
    const float* u0  = ws + OFF_U0;
    const float* mk0 = ws + OFF_MK0;
    const float* u1  = ws + OFF_U1;
    const float* a0  = ws + OFF_A0;
    const float* ak0 = ws + OFF_AK0;
    const float* a1  = ws + OFF_A1;
    const float* Mst = ws + OFF_MST;
    const float* Ast = ws + OFF_AST;
    float* scal = ws + OFF_SCAL;

    int gi  = (g << 8) + x;
    int cgi = c * GM + gi;
    float ak = ak0[gi], mk = mk0[cgi];
    float den0 = a0[gi] * ak;  den0 = (den0 == 0.f) ? 1e-8f : den0;
    float t0 = u0[cgi] * mk / den0;
    float den1 = a1[gi] * ak;  den1 = (den1 == 0.f) ? 1e-8f : den1;
    float t1 = u1[cgi] * mk / den1;

    t0 = waveReduceMax(t0);
    t1 = waveReduceMax(t1);
    __shared__ float s0[4], s1[4];
    int wid = threadIdx.x >> 6, lane = threadIdx.x & 63;
    if (lane == 0) { s0[wid] = t0; s1[wid] = t1; }
    __syncthreads();
    if (threadIdx.x == 0) {
        float m0 = s0[0], m1 = s1[0];
        #pragma unroll
        for (int w = 1; w < 4; ++w) { m0 = fmaxf(m0, s0[w]); m1 = fmaxf(m1, s1[w]); }
        float w1 = fminf(fmaxf(pw[1], 1e-10f), 1.0f);
        float w2 = fminf(fmaxf(pw[2], 1e-10f), 1.0f);
        float A = Ast[g];  A = (A == 0.f) ? 1e-8f : A;
        float uk = Mst[c * G + g] / A;            // l-th power with l+1=1 -> identity
        uk += w1 * (m0 + 1e-8f);
        uk += w2 * sqrtf(m1 + 1e-8f);             // exponent 1/2 -> sqrt
        uk *= (1.0f / 3.0f);                      // / MAXLEN
        atomicAdd(&scal[2], logf(uk + 1e-8f));
    }
}

__global__ void finalK(const float* __restrict__ ws, float* __restrict__ out) {
    const float* scal = ws + OFF_SCAL;
    out[C * G * D + 0] = scal[0] / (float)(C * EDGES);          // L_info mean
    out[C * G * D + 1] = -scal[2] / (float)(C * G);             // L_path mean
    out[C * G * D + 2] = scal[1] / (2.0f * (float)G * (float)C);// L_l2 mean
}

extern "C" void kernel_launch(void* const* d_in, const int* in_sizes, int n_in,
                              void* d_out, int out_size, void* d_ws, size_t ws_size,
                              hipStream_t stream) {
    const float* hg  = (const float*)d_in[0];
    const float* H   = (const float*)d_in[1];
    const float* pw  = (const float*)d_in[2];
    const float* sij = (const float*)d_in[3];
    const int*   ei  = (const int*)d_in[4];
    // d_in[5] = batch (unused: batch[src] == src >> 8)
    const int*   s   = (const int*)d_in[6];
    const int*   t   = (const int*)d_in[7];
    float* out = (float*)d_out;
    float* ws  = (float*)d_ws;

    hipMemsetAsync(d_ws, 0, WS_FLOATS * sizeof(float), stream);
    passA<<<EDGES / 256, 256, 0, stream>>>(sij, ei, s, t, ws);
    passB<<<EDGES / 256, 256, 0, stream>>>(sij, ei, ws);
    embK<<<C * G, D, 0, stream>>>(hg, H, out);
    pathK<<<C * G, M, 0, stream>>>(pw, ws);
    finalK<<<1, 1, 0, stream>>>(ws, out);
}

// Round 2
// 45.886 us; speedup vs baseline: 3.3338x; 3.3338x over previous
//
#include <hip/hip_runtime.h>
#include <math.h>

#define G 256
#define M 256
#define NNODES (G*M)
#define EDGES (NNODES*16)   // 1,048,576
#define C 3
#define K 5
#define D 128
#define GM (G*M)            // 65536

// Workspace layout (floats):
#define OFF_U0   0
#define OFF_MK0  196608
#define OFF_U1   393216
#define OFF_A0   589824
#define OFF_AK0  655360
#define OFF_A1   720896
#define OFF_MST  786432
#define OFF_AST  787200
#define ZERO_FLOATS 787456          // everything above must be zeroed each call
// per-block partials (written unconditionally, no zeroing needed)
#define NB_A     1024               // passA blocks
#define OFF_PINFO 787456
#define OFF_PL2   (OFF_PINFO + NB_A)
#define OFF_PPATH (OFF_PL2 + NB_A)  // C*G = 768
#define WS_FLOATS (OFF_PPATH + C*G)

__device__ __forceinline__ float waveReduceSum(float v) {
    #pragma unroll
    for (int o = 32; o > 0; o >>= 1) v += __shfl_xor(v, o, 64);
    return v;
}
__device__ __forceinline__ float waveReduceMax(float v) {
    #pragma unroll
    for (int o = 32; o > 0; o >>= 1) v = fmaxf(v, __shfl_xor(v, o, 64));
    return v;
}

// Pass A: scatter row-s / col-t slices of Mdj & Adj, plus fused L_info/L_l2 sums.
// Grid-stride over edges; per-block partial sums stored (NO same-address atomics).
__global__ void passA(const float* __restrict__ sij, const int* __restrict__ ei,
                      const int* __restrict__ s, const int* __restrict__ t,
                      float* __restrict__ ws) {
    float* u0  = ws + OFF_U0;
    float* mk0 = ws + OFF_MK0;
    float* a0  = ws + OFF_A0;
    float* ak0 = ws + OFF_AK0;
    float* Mst = ws + OFF_MST;
    float* Ast = ws + OFF_AST;

    float info = 0.f, l2 = 0.f;
    for (int e = blockIdx.x * blockDim.x + threadIdx.x; e < EDGES;
         e += NB_A * 256) {
        int src = ei[e], dst = ei[EDGES + e];
        int g = src >> 8;             // batch[src] = src / M, M = 256
        int r = src & 255;
        int c = dst - (g << 8);       // dst local (same group by construction)
        int sg = s[g], tg = t[g];
        bool isr = (r == sg), isc = (c == tg);
        float v[C];
        #pragma unroll
        for (int cc = 0; cc < C; ++cc) v[cc] = sij[cc * EDGES + e];
        if (isr) {
            #pragma unroll
            for (int cc = 0; cc < C; ++cc) atomicAdd(&u0[cc * GM + (g << 8) + c], v[cc]);
            atomicAdd(&a0[(g << 8) + c], 1.0f);
        }
        if (isc) {
            #pragma unroll
            for (int cc = 0; cc < C; ++cc) atomicAdd(&mk0[cc * GM + (g << 8) + r], v[cc]);
            atomicAdd(&ak0[(g << 8) + r], 1.0f);
        }
        if (isr && isc) {
            #pragma unroll
            for (int cc = 0; cc < C; ++cc) atomicAdd(&Mst[cc * G + g], v[cc]);
            atomicAdd(&Ast[g], 1.0f);
        }
        #pragma unroll
        for (int cc = 0; cc < C; ++cc) {
            float x = v[cc];
            info += x * logf(x * 2.0f + 1e-6f)
                  + (1.0f - x) * logf((1.0f - x) / 0.500001f + 1e-6f);
            l2 += x * x;
        }
    }
    // block reduction -> one plain store per block
    info = waveReduceSum(info);
    l2 = waveReduceSum(l2);
    __shared__ float sInfo[4], sL2[4];
    int wid = threadIdx.x >> 6, lane = threadIdx.x & 63;
    if (lane == 0) { sInfo[wid] = info; sL2[wid] = l2; }
    __syncthreads();
    if (threadIdx.x == 0) {
        float i2 = 0.f, l = 0.f;
        #pragma unroll
        for (int w = 0; w < 4; ++w) { i2 += sInfo[w]; l += sL2[w]; }
        ws[OFF_PINFO + blockIdx.x] = i2;
        ws[OFF_PL2 + blockIdx.x] = l;
    }
}

// Pass B: u1 = u0 @ Mdj (per class), a1 = a0 @ Adj (class-independent), edge-wise.
__global__ void passB(const float* __restrict__ sij, const int* __restrict__ ei,
                      float* __restrict__ ws) {
    int e = blockIdx.x * blockDim.x + threadIdx.x;
    if (e >= EDGES) return;
    const float* u0 = ws + OFF_U0;
    const float* a0 = ws + OFF_A0;
    float* u1 = ws + OFF_U1;
    float* a1 = ws + OFF_A1;
    int src = ei[e], dst = ei[EDGES + e];
    int g = src >> 8;
    int r = src & 255;
    int c = dst - (g << 8);
    float ar = a0[(g << 8) + r];
    if (ar == 0.0f) return;   // u0[g][r]==0 too (sij>0), nothing to scatter
    atomicAdd(&a1[(g << 8) + c], ar);
    #pragma unroll
    for (int cc = 0; cc < C; ++cc) {
        float ur = u0[cc * GM + (g << 8) + r];
        atomicAdd(&u1[cc * GM + (g << 8) + c], ur * sij[cc * EDGES + e]);
    }
}

// H_emb: per (c,g): scores = hg[g] . H[c][k], softmax over K, out = att @ H[c]
__global__ void embK(const float* __restrict__ hg, const float* __restrict__ H,
                     float* __restrict__ out) {
    int b = blockIdx.x;          // c*G + g
    int c = b / G, g = b - c * G;
    int d = threadIdx.x;         // 128 threads
    float h = hg[g * D + d];
    __shared__ float sc[K];
    __shared__ float att[K];
    if (threadIdx.x < K) sc[threadIdx.x] = 0.f;
    __syncthreads();
    #pragma unroll
    for (int k = 0; k < K; ++k) {
        float p = h * H[(c * K + k) * D + d];
        p = waveReduceSum(p);
        if ((threadIdx.x & 63) == 0) atomicAdd(&sc[k], p);
    }
    __syncthreads();
    if (threadIdx.x == 0) {
        float m = sc[0];
        #pragma unroll
        for (int k = 1; k < K; ++k) m = fmaxf(m, sc[k]);
        float sum = 0.f, ex[K];
        #pragma unroll
        for (int k = 0; k < K; ++k) { ex[k] = expf(sc[k] - m); sum += ex[k]; }
        #pragma unroll
        for (int k = 0; k < K; ++k) att[k] = ex[k] / sum;
    }
    __syncthreads();
    float o = 0.f;
    #pragma unroll
    for (int k = 0; k < K; ++k) o += att[k] * H[(c * K + k) * D + d];
    out[(c * G + g) * D + d] = o;
}

// Path loss finalize: per (c,g) block max over M -> per-block log stored.
__global__ void pathK(const float* __restrict__ pw, float* __restrict__ ws) {
    int b = blockIdx.x;          // c*G + g
    int c = b / G, g = b - c * G;
    int x = threadIdx.x;         // 256 threads
    const float* u0  = ws + OFF_U0;
    const float* mk0 = ws + OFF_MK0;
    const float* u1  = ws + OFF_U1;
    const float* a0  = ws + OFF_A0;
    const float* ak0 = ws + OFF_AK0;
    const float* a1  = ws + OFF_A1;
    const float* Mst = ws + OFF_MST;
    const float* Ast = ws + OFF_AST;

    int gi  = (g << 8) + x;
    int cgi = c * GM + gi;
    float ak = ak0[gi], mk = mk0[cgi];
    float den0 = a0[gi] * ak;  den0 = (den0 == 0.f) ? 1e-8f : den0;
    float t0 = u0[cgi] * mk / den0;
    float den1 = a1[gi] * ak;  den1 = (den1 == 0.f) ? 1e-8f : den1;
    float t1 = u1[cgi] * mk / den1;

    t0 = waveReduceMax(t0);
    t1 = waveReduceMax(t1);
    __shared__ float s0[4], s1[4];
    int wid = threadIdx.x >> 6, lane = threadIdx.x & 63;
    if (lane == 0) { s0[wid] = t0; s1[wid] = t1; }
    __syncthreads();
    if (threadIdx.x == 0) {
        float m0 = s0[0], m1 = s1[0];
        #pragma unroll
        for (int w = 1; w < 4; ++w) { m0 = fmaxf(m0, s0[w]); m1 = fmaxf(m1, s1[w]); }
        float w1 = fminf(fmaxf(pw[1], 1e-10f), 1.0f);
        float w2 = fminf(fmaxf(pw[2], 1e-10f), 1.0f);
        float A = Ast[g];  A = (A == 0.f) ? 1e-8f : A;
        float uk = Mst[c * G + g] / A;            // l-th power with l+1=1 -> identity
        uk += w1 * (m0 + 1e-8f);
        uk += w2 * sqrtf(m1 + 1e-8f);             // exponent 1/2 -> sqrt
        uk *= (1.0f / 3.0f);                      // / MAXLEN
        ws[OFF_PPATH + b] = logf(uk + 1e-8f);
    }
}

// Final reduce of all per-block partials -> 3 scalar outputs. One block.
__global__ void finalK(const float* __restrict__ ws, float* __restrict__ out) {
    int tid = threadIdx.x;       // 256 threads
    float info = 0.f, l2 = 0.f, path = 0.f;
    for (int i = tid; i < NB_A; i += 256) {
        info += ws[OFF_PINFO + i];
        l2   += ws[OFF_PL2 + i];
    }
    for (int i = tid; i < C * G; i += 256) path += ws[OFF_PPATH + i];
    info = waveReduceSum(info);
    l2   = waveReduceSum(l2);
    path = waveReduceSum(path);
    __shared__ float sI[4], sL[4], sP[4];
    int wid = tid >> 6, lane = tid & 63;
    if (lane == 0) { sI[wid] = info; sL[wid] = l2; sP[wid] = path; }
    __syncthreads();
    if (tid == 0) {
        float i2 = 0.f, l = 0.f, p = 0.f;
        #pragma unroll
        for (int w = 0; w < 4; ++w) { i2 += sI[w]; l += sL[w]; p += sP[w]; }
        out[C * G * D + 0] = i2 / (float)(C * EDGES);            // L_info mean
        out[C * G * D + 1] = -p / (float)(C * G);                // L_path mean
        out[C * G * D + 2] = l / (2.0f * (float)G * (float)C);   // L_l2 mean
    }
}

extern "C" void kernel_launch(void* const* d_in, const int* in_sizes, int n_in,
                              void* d_out, int out_size, void* d_ws, size_t ws_size,
                              hipStream_t stream) {
    const float* hg  = (const float*)d_in[0];
    const float* H   = (const float*)d_in[1];
    const float* pw  = (const float*)d_in[2];
    const float* sij = (const float*)d_in[3];
    const int*   ei  = (const int*)d_in[4];
    // d_in[5] = batch (unused: batch[src] == src >> 8)
    const int*   s   = (const int*)d_in[6];
    const int*   t   = (const int*)d_in[7];
    float* out = (float*)d_out;
    float* ws  = (float*)d_ws;

    hipMemsetAsync(d_ws, 0, ZERO_FLOATS * sizeof(float), stream);
    passA<<<NB_A, 256, 0, stream>>>(sij, ei, s, t, ws);
    passB<<<EDGES / 256, 256, 0, stream>>>(sij, ei, ws);
    embK<<<C * G, D, 0, stream>>>(hg, H, out);
    pathK<<<C * G, M, 0, stream>>>(pw, ws);
    finalK<<<1, 256, 0, stream>>>(ws, out);
}

// Round 3
// 42.505 us; speedup vs baseline: 3.5989x; 1.0795x over previous
//
#include <hip/hip_runtime.h>
#include <math.h>

#define G 256
#define M 256
#define NNODES (G*M)
#define EDGES (NNODES*16)   // 1,048,576
#define C 3
#define K 5
#define D 128
#define GM (G*M)            // 65536

// Workspace layout (floats):
#define OFF_U0   0
#define OFF_MK0  196608
#define OFF_U1   393216
#define OFF_A0   589824
#define OFF_AK0  655360
#define OFF_A1   720896
#define OFF_MST  786432
#define OFF_AST  787200
#define ZERO_FLOATS 787456          // everything above must be zeroed each call
// per-block partials (written unconditionally, no zeroing needed)
#define NB_EDGE  1024               // edge blocks in passA/passB (256 thr x 4 edges)
#define NB_EMB   384                // emb blocks appended to passA grid (2 pairs each)
#define OFF_PINFO 787456
#define OFF_PL2   (OFF_PINFO + NB_EDGE)
#define OFF_PPATH (OFF_PL2 + NB_EDGE)  // C*G = 768
#define WS_FLOATS (OFF_PPATH + C*G)

__device__ __forceinline__ float waveReduceSum(float v) {
    #pragma unroll
    for (int o = 32; o > 0; o >>= 1) v += __shfl_xor(v, o, 64);
    return v;
}
__device__ __forceinline__ float waveReduceMax(float v) {
    #pragma unroll
    for (int o = 32; o > 0; o >>= 1) v = fmaxf(v, __shfl_xor(v, o, 64));
    return v;
}

// Pass A (blocks 0..NB_EDGE-1): scatter row-s / col-t slices of Mdj & Adj,
// fused L_info/L_l2 partial sums. 4 edges/thread, vectorized loads.
// Blocks NB_EDGE.. : H_emb (independent work, hidden under passA).
__global__ void passA(const float* __restrict__ sij, const int* __restrict__ ei,
                      const int* __restrict__ s, const int* __restrict__ t,
                      const float* __restrict__ hg, const float* __restrict__ H,
                      float* __restrict__ out, float* __restrict__ ws) {
    __shared__ float sc[2][K];
    __shared__ float att[2][K];
    __shared__ float sInfo[4], sL2[4];

    if (blockIdx.x >= NB_EDGE) {
        // ---- H_emb: 2 (c,g) pairs per block, 128 threads each ----
        int half = threadIdx.x >> 7;           // 0 or 1
        int d = threadIdx.x & 127;
        int pair = (blockIdx.x - NB_EDGE) * 2 + half;   // c*G + g
        int c = pair / G, g = pair - c * G;
        float h = hg[g * D + d];
        if (d < K) sc[half][d] = 0.f;
        __syncthreads();
        #pragma unroll
        for (int k = 0; k < K; ++k) {
            float p = h * H[(c * K + k) * D + d];
            p = waveReduceSum(p);
            if ((threadIdx.x & 63) == 0) atomicAdd(&sc[half][k], p);
        }
        __syncthreads();
        if (d == 0) {
            float m = sc[half][0];
            #pragma unroll
            for (int k = 1; k < K; ++k) m = fmaxf(m, sc[half][k]);
            float sum = 0.f, ex[K];
            #pragma unroll
            for (int k = 0; k < K; ++k) { ex[k] = expf(sc[half][k] - m); sum += ex[k]; }
            #pragma unroll
            for (int k = 0; k < K; ++k) att[half][k] = ex[k] / sum;
        }
        __syncthreads();
        float o = 0.f;
        #pragma unroll
        for (int k = 0; k < K; ++k) o += att[half][k] * H[(c * K + k) * D + d];
        out[pair * D + d] = o;
        return;
    }

    // ---- edge pass ----
    float* u0  = ws + OFF_U0;
    float* mk0 = ws + OFF_MK0;
    float* a0  = ws + OFF_A0;
    float* ak0 = ws + OFF_AK0;
    float* Mst = ws + OFF_MST;
    float* Ast = ws + OFF_AST;

    int tid = blockIdx.x * 256 + threadIdx.x;   // 0..262143
    int e0 = tid * 4;
    int4 src4 = *(const int4*)(ei + e0);
    int4 dst4 = *(const int4*)(ei + EDGES + e0);
    float4 v0 = *(const float4*)(sij + 0 * EDGES + e0);
    float4 v1 = *(const float4*)(sij + 1 * EDGES + e0);
    float4 v2 = *(const float4*)(sij + 2 * EDGES + e0);

    const int* srcp = (const int*)&src4;
    const int* dstp = (const int*)&dst4;
    const float* v0p = (const float*)&v0;
    const float* v1p = (const float*)&v1;
    const float* v2p = (const float*)&v2;

    float info = 0.f, l2 = 0.f;
    #pragma unroll
    for (int j = 0; j < 4; ++j) {
        int src = srcp[j], dst = dstp[j];
        int g = src >> 8;
        int r = src & 255;
        int c = dst - (g << 8);
        int sg = s[g], tg = t[g];
        float v[C] = { v0p[j], v1p[j], v2p[j] };
        if (r == sg) {
            #pragma unroll
            for (int cc = 0; cc < C; ++cc) atomicAdd(&u0[cc * GM + (g << 8) + c], v[cc]);
            atomicAdd(&a0[(g << 8) + c], 1.0f);
            if (c == tg) {
                #pragma unroll
                for (int cc = 0; cc < C; ++cc) atomicAdd(&Mst[cc * G + g], v[cc]);
                atomicAdd(&Ast[g], 1.0f);
            }
        }
        if (c == tg) {
            #pragma unroll
            for (int cc = 0; cc < C; ++cc) atomicAdd(&mk0[cc * GM + (g << 8) + r], v[cc]);
            atomicAdd(&ak0[(g << 8) + r], 1.0f);
        }
        #pragma unroll
        for (int cc = 0; cc < C; ++cc) {
            float x = v[cc];
            info += x * __logf(x * 2.0f + 1e-6f)
                  + (1.0f - x) * __logf((1.0f - x) / 0.500001f + 1e-6f);
            l2 += x * x;
        }
    }
    info = waveReduceSum(info);
    l2 = waveReduceSum(l2);
    int wid = threadIdx.x >> 6, lane = threadIdx.x & 63;
    if (lane == 0) { sInfo[wid] = info; sL2[wid] = l2; }
    __syncthreads();
    if (threadIdx.x == 0) {
        float i2 = 0.f, l = 0.f;
        #pragma unroll
        for (int w = 0; w < 4; ++w) { i2 += sInfo[w]; l += sL2[w]; }
        ws[OFF_PINFO + blockIdx.x] = i2;
        ws[OFF_PL2 + blockIdx.x] = l;
    }
}

// Pass B: u1 = u0 @ Mdj (per class), a1 = a0 @ Adj, edge-wise, 4 edges/thread.
__global__ void passB(const float* __restrict__ sij, const int* __restrict__ ei,
                      float* __restrict__ ws) {
    const float* u0 = ws + OFF_U0;
    const float* a0 = ws + OFF_A0;
    float* u1 = ws + OFF_U1;
    float* a1 = ws + OFF_A1;

    int tid = blockIdx.x * 256 + threadIdx.x;
    int e0 = tid * 4;
    int4 src4 = *(const int4*)(ei + e0);
    int4 dst4 = *(const int4*)(ei + EDGES + e0);
    const int* srcp = (const int*)&src4;
    const int* dstp = (const int*)&dst4;

    #pragma unroll
    for (int j = 0; j < 4; ++j) {
        int src = srcp[j], dst = dstp[j];
        int g = src >> 8;
        int r = src & 255;
        int c = dst - (g << 8);
        float ar = a0[(g << 8) + r];
        if (ar == 0.0f) continue;   // u0[g][r]==0 too (sij>0)
        atomicAdd(&a1[(g << 8) + c], ar);
        int e = e0 + j;
        #pragma unroll
        for (int cc = 0; cc < C; ++cc) {
            float ur = u0[cc * GM + (g << 8) + r];
            atomicAdd(&u1[cc * GM + (g << 8) + c], ur * sij[cc * EDGES + e]);
        }
    }
}

// Path loss finalize: per (c,g) block max over M -> per-block log stored.
__global__ void pathK(const float* __restrict__ pw, float* __restrict__ ws) {
    int b = blockIdx.x;          // c*G + g
    int c = b / G, g = b - c * G;
    int x = threadIdx.x;         // 256 threads
    const float* u0  = ws + OFF_U0;
    const float* mk0 = ws + OFF_MK0;
    const float* u1  = ws + OFF_U1;
    const float* a0  = ws + OFF_A0;
    const float* ak0 = ws + OFF_AK0;
    const float* a1  = ws + OFF_A1;
    const float* Mst = ws + OFF_MST;
    const float* Ast = ws + OFF_AST;

    int gi  = (g << 8) + x;
    int cgi = c * GM + gi;
    float ak = ak0[gi], mk = mk0[cgi];
    float den0 = a0[gi] * ak;  den0 = (den0 == 0.f) ? 1e-8f : den0;
    float t0 = u0[cgi] * mk / den0;
    float den1 = a1[gi] * ak;  den1 = (den1 == 0.f) ? 1e-8f : den1;
    float t1 = u1[cgi] * mk / den1;

    t0 = waveReduceMax(t0);
    t1 = waveReduceMax(t1);
    __shared__ float s0[4], s1[4];
    int wid = threadIdx.x >> 6, lane = threadIdx.x & 63;
    if (lane == 0) { s0[wid] = t0; s1[wid] = t1; }
    __syncthreads();
    if (threadIdx.x == 0) {
        float m0 = s0[0], m1 = s1[0];
        #pragma unroll
        for (int w = 1; w < 4; ++w) { m0 = fmaxf(m0, s0[w]); m1 = fmaxf(m1, s1[w]); }
        float w1 = fminf(fmaxf(pw[1], 1e-10f), 1.0f);
        float w2 = fminf(fmaxf(pw[2], 1e-10f), 1.0f);
        float A = Ast[g];  A = (A == 0.f) ? 1e-8f : A;
        float uk = Mst[c * G + g] / A;            // l+1=1 -> identity power
        uk += w1 * (m0 + 1e-8f);
        uk += w2 * sqrtf(m1 + 1e-8f);             // exponent 1/2 -> sqrt
        uk *= (1.0f / 3.0f);                      // / MAXLEN
        ws[OFF_PPATH + b] = __logf(uk + 1e-8f);
    }
}

// Final reduce of all per-block partials -> 3 scalar outputs. One block.
__global__ void finalK(const float* __restrict__ ws, float* __restrict__ out) {
    int tid = threadIdx.x;       // 256 threads
    float info = 0.f, l2 = 0.f, path = 0.f;
    for (int i = tid; i < NB_EDGE; i += 256) {
        info += ws[OFF_PINFO + i];
        l2   += ws[OFF_PL2 + i];
    }
    for (int i = tid; i < C * G; i += 256) path += ws[OFF_PPATH + i];
    info = waveReduceSum(info);
    l2   = waveReduceSum(l2);
    path = waveReduceSum(path);
    __shared__ float sI[4], sL[4], sP[4];
    int wid = tid >> 6, lane = tid & 63;
    if (lane == 0) { sI[wid] = info; sL[wid] = l2; sP[wid] = path; }
    __syncthreads();
    if (tid == 0) {
        float i2 = 0.f, l = 0.f, p = 0.f;
        #pragma unroll
        for (int w = 0; w < 4; ++w) { i2 += sI[w]; l += sL[w]; p += sP[w]; }
        out[C * G * D + 0] = i2 / (float)(C * EDGES);            // L_info mean
        out[C * G * D + 1] = -p / (float)(C * G);                // L_path mean
        out[C * G * D + 2] = l / (2.0f * (float)G * (float)C);   // L_l2 mean
    }
}

extern "C" void kernel_launch(void* const* d_in, const int* in_sizes, int n_in,
                              void* d_out, int out_size, void* d_ws, size_t ws_size,
                              hipStream_t stream) {
    const float* hg  = (const float*)d_in[0];
    const float* H   = (const float*)d_in[1];
    const float* pw  = (const float*)d_in[2];
    const float* sij = (const float*)d_in[3];
    const int*   ei  = (const int*)d_in[4];
    // d_in[5] = batch (unused: batch[src] == src >> 8)
    const int*   s   = (const int*)d_in[6];
    const int*   t   = (const int*)d_in[7];
    float* out = (float*)d_out;
    float* ws  = (float*)d_ws;

    hipMemsetAsync(d_ws, 0, ZERO_FLOATS * sizeof(float), stream);
    passA<<<NB_EDGE + NB_EMB, 256, 0, stream>>>(sij, ei, s, t, hg, H, out, ws);
    passB<<<NB_EDGE, 256, 0, stream>>>(sij, ei, ws);
    pathK<<<C * G, M, 0, stream>>>(pw, ws);
    finalK<<<1, 256, 0, stream>>>(ws, out);
}